// Round 10
// baseline (368.369 us; speedup 1.0000x reference)
//
#include <hip/hip_runtime.h>
#include <stdint.h>

// T5-style attention, MI355X gfx950.
// B=2 S=2048 D=1024 H=16 DK=64, NUM_BUCKETS=32, MAX_DISTANCE=128.
// R21 = R20 with flash split-K within the block: 512 threads / 8 waves;
// waves 0-3 do KV[0,1024), waves 4-7 do KV[1024,2048) for the same 128 q-rows.
// Static-max softmax => unnormalized (o,l) partials add exactly; merged via
// LDS in the epilogue. 2 blocks/CU -> 4 waves/SIMD (2x TLP), LDS-reads-per-
// output unchanged (R15 lesson). gemm_qkv/gemm_out/cvt_all unchanged from R20.

typedef unsigned short u16;
typedef __attribute__((ext_vector_type(8))) short short8;
typedef __attribute__((ext_vector_type(4))) float float4v;
typedef __attribute__((ext_vector_type(4))) u16 ushort4v;
typedef __attribute__((ext_vector_type(4))) uint32_t uint4v;

typedef __attribute__((address_space(1))) void void_g;
typedef __attribute__((address_space(3))) void void_l;

#define L2E 1.4426950408889634f

__device__ __forceinline__ u16 f2b(float f) {
  union { float f; uint32_t u; } v; v.f = f;
  uint32_t r = (v.u + 0x7fffu + ((v.u >> 16) & 1u)) >> 16;
  return (u16)r;
}
__device__ __forceinline__ u16 f2b_fast(float f) {
  union { float f; uint32_t u; } v; v.f = f;
  return (u16)((v.u + 0x8000u) >> 16);
}
__device__ __forceinline__ uint32_t cvt_pk_bf16(float lo, float hi) {
  uint32_t r;
  asm("v_cvt_pk_bf16_f32 %0, %1, %2" : "=v"(r) : "v"(lo), "v"(hi));
  return r;
}

// ---------------- fused fp32->bf16 convert + bias table -------------------------
__global__ void cvt_all(const float* __restrict__ x,  const float* __restrict__ qw,
                        const float* __restrict__ kw, const float* __restrict__ vw,
                        const float* __restrict__ ow, const float* __restrict__ rel_bias,
                        u16* __restrict__ xb, u16* __restrict__ wqkv, u16* __restrict__ owb,
                        float* __restrict__ biasT) {
  int bi = blockIdx.x;
  if (bi >= 8192) {
    int idx = (bi - 8192) * 256 + threadIdx.x;   // 0..65535
    int h = idx >> 12, t = idx & 4095;
    if (t > 4094) { biasT[h * 4096 + 4095] = -1.0e4f; return; }
    int d = t - 2047;
    int n = -d;
    int ret = (n < 0) ? 16 : 0;
    int na = (n < 0) ? -n : n;
    int bucket;
    if (na < 8) {
      bucket = ret + na;
    } else {
      float v = logf((float)na / 8.0f) / logf(16.0f) * 8.0f;
      int vi = 8 + (int)v;
      bucket = ret + (vi > 15 ? 15 : vi);
    }
    biasT[h * 4096 + t] = (rel_bias[bucket * 16 + h] - 8.0f) * L2E;
    return;
  }
  int i = bi * 256 + threadIdx.x;
  const float* s; u16* d; int off;
  if (i < 1048576)      { s = x;  d = xb;              off = i; }
  else if (i < 1310720) { s = qw; d = wqkv;            off = i - 1048576; }
  else if (i < 1572864) { s = kw; d = wqkv + 1048576;  off = i - 1310720; }
  else if (i < 1835008) { s = vw; d = wqkv + 2097152;  off = i - 1572864; }
  else                  { s = ow; d = owb;             off = i - 1835008; }
  float4v v = ((const float4v*)s)[off];
  ushort4v o;
  o.x = f2b(v.x); o.y = f2b(v.y); o.z = f2b(v.z); o.w = f2b(v.w);
  ((ushort4v*)d)[off] = o;
}

// ---------------- QKV GEMM: [4096,3072] = xb[4096,1024] * wqkv[3072,1024]^T ----
// 128x128 tile, BK=64, single-buffered LDS (34816 B -> 3 blocks/CU).
// XCD-chunked swizzle. Q/K epilogue via LDS transpose; V epilogue in registers.
__global__ __launch_bounds__(256, 3)
void gemm_qkv(const u16* __restrict__ A, const u16* __restrict__ W,
              u16* __restrict__ qkb, u16* __restrict__ vTp) {
  const int K = 1024;
  __shared__ __align__(16) char SM[34816];
  u16* As = (u16*)SM;            // [kk][row][32]
  u16* Bs = (u16*)(SM + 16384);
  const int tid = threadIdx.x;
  const int wid = tid >> 6;
  const int lane = tid & 63;
  const int row16 = lane & 15, oct = lane >> 4;
  // bijective XCD chunk: 768 blocks, 96 per XCD
  const int lin = blockIdx.x + blockIdx.y * 32;     // grid (32,24) x-major
  const int V = (lin & 7) * 96 + (lin >> 3);
  const int bx = V & 31, by = V >> 5;
  const int tm = bx * 128, tn = by * 128;
  const int wm = (wid & 1) * 64, wn = (wid >> 1) * 64;
  const int srow = lane >> 2;
  const int sc = (lane & 3) * 8;
  float4v acc[4][4] = {};
  for (int k0 = 0; k0 < K; k0 += 64) {
    __syncthreads();
#pragma unroll
    for (int i = 0; i < 4; i++) {
      const int idx = i * 4 + wid;
      const int kk = idx & 1;
      const int rb = idx >> 1;
      const int r = rb * 16 + srow;
      const int c = kk * 32 + sc;
      __builtin_amdgcn_global_load_lds((void_g*)(A + (size_t)(tm + r) * K + k0 + c),
                                       (void_l*)(As + (kk * 128 + rb * 16) * 32), 16, 0, 0);
      __builtin_amdgcn_global_load_lds((void_g*)(W + (size_t)(tn + r) * K + k0 + c),
                                       (void_l*)(Bs + (kk * 128 + rb * 16) * 32), 16, 0, 0);
    }
    __syncthreads();
#pragma unroll
    for (int kk = 0; kk < 2; kk++) {
      short8 af[4], bfr[4];
#pragma unroll
      for (int mi = 0; mi < 4; mi++)
        af[mi] = *(const short8*)(As + (kk * 128 + wm + mi * 16 + row16) * 32 + oct * 8);
#pragma unroll
      for (int ni = 0; ni < 4; ni++)
        bfr[ni] = *(const short8*)(Bs + (kk * 128 + wn + ni * 16 + row16) * 32 + oct * 8);
#pragma unroll
      for (int mi = 0; mi < 4; mi++)
#pragma unroll
        for (int ni = 0; ni < 4; ni++)
          acc[mi][ni] = __builtin_amdgcn_mfma_f32_16x16x32_bf16(af[mi], bfr[ni], acc[mi][ni], 0, 0, 0);
    }
  }

  if (tn < 2048) {
    // Q/K: stage 128x128 bf16 tile in LDS (pitch 136), row-major out
    u16* Es = (u16*)SM;
    __syncthreads();
#pragma unroll
    for (int mi = 0; mi < 4; mi++)
#pragma unroll
      for (int ni = 0; ni < 4; ni++)
#pragma unroll
        for (int r = 0; r < 4; r++)
          Es[(wm + mi * 16 + oct * 4 + r) * 136 + wn + ni * 16 + row16] = f2b(acc[mi][ni][r]);
    __syncthreads();
#pragma unroll
    for (int it = 0; it < 8; it++) {
      int idx = it * 256 + tid;
      int row = idx >> 4, c = idx & 15;
      short8 v = *(const short8*)(Es + row * 136 + c * 8);
      *(short8*)(qkb + (size_t)(tm + row) * 2048 + tn + c * 8) = v;
    }
  } else {
    // V: direct register epilogue. Stored slot u = 8*oct + 4*(mi&1) + r holds
    // acc row; thread stores 8 contiguous bf16 per (bb, ni).
    const int h0 = (tn - 2048) >> 6;
    const int b = tm >> 11;
    const int s0 = tm & 2047;
#pragma unroll
    for (int ni = 0; ni < 4; ni++) {
      const int dg = wn + ni * 16 + row16;
      const int head = h0 + (dg >> 6), d = dg & 63;
      u16* vdst = vTp + ((size_t)((b * 16 + head) * 64 + d)) * 2048 + s0 + wm + oct * 8;
#pragma unroll
      for (int bb = 0; bb < 2; bb++) {
        uint4v pw;
        pw.x = cvt_pk_bf16(acc[2 * bb][ni][0], acc[2 * bb][ni][1]);
        pw.y = cvt_pk_bf16(acc[2 * bb][ni][2], acc[2 * bb][ni][3]);
        pw.z = cvt_pk_bf16(acc[2 * bb + 1][ni][0], acc[2 * bb + 1][ni][1]);
        pw.w = cvt_pk_bf16(acc[2 * bb + 1][ni][2], acc[2 * bb + 1][ni][3]);
        *(uint4v*)(vdst + bb * 32) = pw;
      }
    }
  }
}

// ---------------- out GEMM: d_out[4096,1024] = ctxb * owb^T (f32 out) ----------
// 64x128 tile, grid (64,8)=512 blocks, 2-phase double-buffered LDS.
// Direct-from-register f32 epilogue (row-major out, no transpose needed).
__global__ __launch_bounds__(256, 2)
void gemm_out(const u16* __restrict__ A, const u16* __restrict__ W,
              float* __restrict__ C) {
  const int K = 1024, N = 1024;
  __shared__ __align__(16) char SM[49152];   // [buf][A 8K | B 16K]
  const int tid = threadIdx.x;
  const int wid = tid >> 6;
  const int lane = tid & 63;
  const int row16 = lane & 15, oct = lane >> 4;
  const int tm = blockIdx.x * 64, tn = blockIdx.y * 128;
  const int wm = (wid & 1) * 32, wn = (wid >> 1) * 64;
  const int srow = lane >> 2;
  const int sc = (lane & 3) * 8;
  float4v acc[2][4] = {};

#define STAGE_OUT(buf, k0)                                                            \
  {                                                                                   \
    u16* Ad = (u16*)(SM + (buf) * 24576);                                             \
    u16* Bd = (u16*)(SM + (buf) * 24576 + 8192);                                      \
    _Pragma("unroll")                                                                 \
    for (int i = 0; i < 2; i++) {                                                     \
      const int idx = i * 4 + wid;                                                    \
      const int kk = idx & 1;                                                         \
      const int rb = idx >> 1;                                                        \
      const int r = rb * 16 + srow;                                                   \
      const int c = kk * 32 + sc;                                                     \
      __builtin_amdgcn_global_load_lds((void_g*)(A + (size_t)(tm + r) * K + (k0) + c),\
                                       (void_l*)(Ad + (kk * 64 + rb * 16) * 32), 16, 0, 0); \
    }                                                                                 \
    _Pragma("unroll")                                                                 \
    for (int i = 0; i < 4; i++) {                                                     \
      const int idx = i * 4 + wid;                                                    \
      const int kk = idx & 1;                                                         \
      const int rb = idx >> 1;                                                        \
      const int r = rb * 16 + srow;                                                   \
      const int c = kk * 32 + sc;                                                     \
      __builtin_amdgcn_global_load_lds((void_g*)(W + (size_t)(tn + r) * K + (k0) + c),\
                                       (void_l*)(Bd + (kk * 128 + rb * 16) * 32), 16, 0, 0); \
    }                                                                                 \
  }

  STAGE_OUT(0, 0);
  __syncthreads();
  for (int t = 0; t < 16; t++) {
    if (t + 1 < 16) STAGE_OUT((t + 1) & 1, (t + 1) * 64);
    const u16* As = (const u16*)(SM + (t & 1) * 24576);
    const u16* Bs = As + 4096;   // 8192 bytes
#pragma unroll
    for (int kk = 0; kk < 2; kk++) {
      short8 af[2], bfr[4];
#pragma unroll
      for (int mi = 0; mi < 2; mi++)
        af[mi] = *(const short8*)(As + (kk * 64 + wm + mi * 16 + row16) * 32 + oct * 8);
#pragma unroll
      for (int ni = 0; ni < 4; ni++)
        bfr[ni] = *(const short8*)(Bs + (kk * 128 + wn + ni * 16 + row16) * 32 + oct * 8);
#pragma unroll
      for (int mi = 0; mi < 2; mi++)
#pragma unroll
        for (int ni = 0; ni < 4; ni++)
          acc[mi][ni] = __builtin_amdgcn_mfma_f32_16x16x32_bf16(af[mi], bfr[ni], acc[mi][ni], 0, 0, 0);
    }
    __syncthreads();
  }
  // direct f32 epilogue: row = tm+wm+mi*16+oct*4+r, col = tn+wn+ni*16+row16.
#pragma unroll
  for (int mi = 0; mi < 2; mi++)
#pragma unroll
    for (int ni = 0; ni < 4; ni++)
#pragma unroll
      for (int r = 0; r < 4; r++)
        C[(size_t)(tm + wm + mi * 16 + oct * 4 + r) * N + tn + wn + ni * 16 + row16] =
            acc[mi][ni][r];
}

// ---------------- flash attention (split-K within block) -----------------------
// grid (16,16,2) x 512 threads = 8 waves. Wave w: q-rows (w&3)*32..+32 of the
// 128-row q-tile, KV half (w>>2). Static-max softmax -> (o,l) partials add
// exactly; merged via LDS epilogue. Single-buffered K/V per half, 2 barriers
// per tile. Swapped QK^T, lane-local P pack, ones-MFMA row-sum as R18.
__global__ __launch_bounds__(512, 4)
void flash_attn(const u16* __restrict__ qkb, const u16* __restrict__ vTp,
                const float* __restrict__ biasT, u16* __restrict__ ctx) {
  const int S = 2048, LDQ = 2048;
  const int lin = blockIdx.x + (blockIdx.y << 4) + (blockIdx.z << 8);
  const int V = (lin & 7) * 64 + (lin >> 3);
  const int qt0 = (V & 15) * 128;
  const int h = (V >> 4) & 15, b = V >> 8;
  const int tid = threadIdx.x, wid = tid >> 6, lane = tid & 63;
  const int row16 = lane & 15, oct = lane >> 4;
  const int qw = wid & 3;          // q-row group
  const int half = wid >> 2;       // KV half

  __shared__ __align__(16) char SM[49664];
  float* biasS = (float*)SM;                        // [0, 8704)
  u16* KsB  = (u16*)(SM + 8704);                    // [half][hd][64][40] 20480 B
  u16* VtsB = (u16*)(SM + 8704 + 20480);            // [half][ks][64][40] 20480 B

  {
    const float* bsrc = biasT + h * 4096 + (1920 - qt0);
    for (int i = tid; i < 544; i += 512)
      ((float4v*)biasS)[i] = ((const float4v*)bsrc)[i];
  }
  const float bias_neg = biasT[h * 4096];          // d <= -128 (bucket 15)
  const float bias_pos = biasT[h * 4096 + 4094];   // d >= +128 (bucket 31)

  const u16* qbase = qkb + ((size_t)b * S + qt0 + qw * 32) * LDQ + h * 64;
  short8 qf[2][2];
#pragma unroll
  for (int f = 0; f < 2; f++)
#pragma unroll
    for (int hd = 0; hd < 2; hd++)
      qf[f][hd] = *(const short8*)(qbase + (size_t)(f * 16 + row16) * LDQ + hd * 32 + oct * 8);

  float4v l_acc[2] = {};
  float4v o_acc[2][4] = {};
  const short8 ones = {0x3F80, 0x3F80, 0x3F80, 0x3F80, 0x3F80, 0x3F80, 0x3F80, 0x3F80};

  const int sr = lane >> 2, c8 = (lane & 3) * 8;
  const int srow = qw * 16 + sr;                   // 0..63, staged by 4 waves/half
  const u16* Kst = qkb + 1024 + ((size_t)b * S + half * 1024 + srow) * LDQ + c8 + h * 64;
  const u16* Vst = vTp + ((size_t)(b * 16 + h) * 64 + srow) * 2048 + half * 1024 + c8;

  u16* KsH  = KsB  + half * 2 * 64 * 40;           // this half's K region
  u16* VtsH = VtsB + half * 2 * 64 * 40;           // this half's V region

  short8 kreg[2], vreg[2];
#pragma unroll
  for (int hd = 0; hd < 2; hd++) kreg[hd] = *(const short8*)(Kst + hd * 32);
#pragma unroll
  for (int ks = 0; ks < 2; ks++) vreg[ks] = *(const short8*)(Vst + ks * 32);

  for (int kt = 0; kt < 1024; kt += 64) {
    __syncthreads();
#pragma unroll
    for (int hd = 0; hd < 2; hd++)
      *(short8*)(KsH + (hd * 64 + srow) * 40 + c8) = kreg[hd];
#pragma unroll
    for (int ks = 0; ks < 2; ks++)
      *(short8*)(VtsH + (ks * 64 + srow) * 40 + c8) = vreg[ks];
    __syncthreads();

    if (kt + 64 < 1024) {
#pragma unroll
      for (int hd = 0; hd < 2; hd++)
        kreg[hd] = *(const short8*)(Kst + (size_t)(kt + 64) * LDQ + hd * 32);
#pragma unroll
      for (int ks = 0; ks < 2; ks++)
        vreg[ks] = *(const short8*)(Vst + (kt + 64) + ks * 32);
    }

    short8 kf[4][2];
#pragma unroll
    for (int st = 0; st < 4; st++)
#pragma unroll
      for (int hd = 0; hd < 2; hd++)
        kf[st][hd] = *(const short8*)(KsH + (hd * 64 + st * 16 + row16) * 40 + oct * 8);

    // swapped QK^T: lane holds S[k = st*16 + oct*4 + r][q = row16]
    float4v sc[2][4];
    __builtin_amdgcn_s_setprio(1);
#pragma unroll
    for (int f = 0; f < 2; f++)
#pragma unroll
      for (int st = 0; st < 4; st++) {
        float4v s = {};
        s = __builtin_amdgcn_mfma_f32_16x16x32_bf16(kf[st][0], qf[f][0], s, 0, 0, 0);
        s = __builtin_amdgcn_mfma_f32_16x16x32_bf16(kf[st][1], qf[f][1], s, 0, 0, 0);
        sc[f][st] = s;
      }
    __builtin_amdgcn_s_setprio(0);

    short8 vf[2][4];
#pragma unroll
    for (int ks = 0; ks < 2; ks++)
#pragma unroll
      for (int ni = 0; ni < 4; ni++)
        vf[ks][ni] = *(const short8*)(VtsH + (ks * 64 + ni * 16 + row16) * 40 + oct * 8);

    // bias + exp (q = row16, k = st*16 + oct*4 + r; global kt = half*1024+kt)
    const int dk = half * 1024 + kt - qt0;
    const bool far = (dk >= 256) || (dk <= -192);
    if (far) {
      const float bc = (dk > 0) ? bias_pos : bias_neg;
#pragma unroll
      for (int f = 0; f < 2; f++)
#pragma unroll
        for (int st = 0; st < 4; st++)
#pragma unroll
          for (int r = 0; r < 4; r++)
            sc[f][st][r] = __builtin_amdgcn_exp2f(__builtin_fmaf(sc[f][st][r], L2E, bc));
    } else {
#pragma unroll
      for (int f = 0; f < 2; f++) {
        const int basef = half * 1024 + kt + oct * 4 - qw * 32 - f * 16 - row16 + 127;
#pragma unroll
        for (int st = 0; st < 4; st++)
#pragma unroll
          for (int r = 0; r < 4; r++)
            sc[f][st][r] = __builtin_amdgcn_exp2f(
                __builtin_fmaf(sc[f][st][r], L2E, biasS[basef + st * 16 + r]));
      }
    }

#pragma unroll
    for (int f = 0; f < 2; f++) {
#pragma unroll
      for (int ks = 0; ks < 2; ks++) {
        uint4v pw;
        pw.x = cvt_pk_bf16(sc[f][2 * ks][0], sc[f][2 * ks][1]);
        pw.y = cvt_pk_bf16(sc[f][2 * ks][2], sc[f][2 * ks][3]);
        pw.z = cvt_pk_bf16(sc[f][2 * ks + 1][0], sc[f][2 * ks + 1][1]);
        pw.w = cvt_pk_bf16(sc[f][2 * ks + 1][2], sc[f][2 * ks + 1][3]);
        short8 pf = __builtin_bit_cast(short8, pw);
        __builtin_amdgcn_s_setprio(1);
#pragma unroll
        for (int ni = 0; ni < 4; ni++)
          o_acc[f][ni] = __builtin_amdgcn_mfma_f32_16x16x32_bf16(pf, vf[ks][ni], o_acc[f][ni], 0, 0, 0);
        l_acc[f] = __builtin_amdgcn_mfma_f32_16x16x32_bf16(pf, ones, l_acc[f], 0, 0, 0);
        __builtin_amdgcn_s_setprio(0);
      }
    }
  }

  // ---- merge halves via LDS (40 f32 per lane-slot; 256 slots = 40960 B) ----
  __syncthreads();                        // all compute done; LDS reusable
  float* MRG = (float*)SM;
  const int slot = (qw * 64 + lane) * 40;
  if (half == 1) {
#pragma unroll
    for (int f = 0; f < 2; f++) {
#pragma unroll
      for (int ni = 0; ni < 4; ni++)
        *(float4v*)(MRG + slot + (f * 4 + ni) * 4) = o_acc[f][ni];
      *(float4v*)(MRG + slot + 32 + f * 4) = l_acc[f];
    }
  }
  __syncthreads();
  if (half == 0) {
#pragma unroll
    for (int f = 0; f < 2; f++) {
      float4v lp = *(const float4v*)(MRG + slot + 32 + f * 4);
      float linv[4];
#pragma unroll
      for (int r = 0; r < 4; r++)
        linv[r] = 1.0f / (l_acc[f][r] + lp[r]);
      const size_t orow = (size_t)b * S + qt0 + qw * 32 + f * 16 + oct * 4;
#pragma unroll
      for (int ni = 0; ni < 4; ni++) {
        float4v op = *(const float4v*)(MRG + slot + (f * 4 + ni) * 4);
#pragma unroll
        for (int r = 0; r < 4; r++)
          ctx[(orow + r) * 1024 + h * 64 + ni * 16 + row16] =
              f2b_fast((o_acc[f][ni][r] + op[r]) * linv[r]);
      }
    }
  }
}

// ---------------- host launcher ------------------------------------------------
extern "C" void kernel_launch(void* const* d_in, const int* in_sizes, int n_in,
                              void* d_out, int out_size, void* d_ws, size_t ws_size,
                              hipStream_t stream) {
  const float* x        = (const float*)d_in[0];
  const float* q_w      = (const float*)d_in[1];
  const float* k_w      = (const float*)d_in[2];
  const float* v_w      = (const float*)d_in[3];
  const float* o_w      = (const float*)d_in[4];
  const float* rel_bias = (const float*)d_in[5];

  char* ws = (char*)d_ws;
  u16*   xb    = (u16*)(ws);                         // [0,8M)   x bf16
  u16*   wqkv  = (u16*)(ws + 8388608);               // [8M,14M) qkv weights bf16
  u16*   owb   = (u16*)(ws + 14680064);              // [14M,16M) o_w bf16
  u16*   qkb   = (u16*)(ws + 16777216);              // [16M,32M) Q|K rows, LDC=2048
  u16*   vTp   = (u16*)(ws + 33554432);              // [32M,40M) V^T permuted
  u16*   ctxb  = (u16*)(ws + 41943040);              // [40M,48M) attention out bf16
  float* biasT = (float*)(ws + 50331648);            // [48M..] bias table

  cvt_all<<<8448, 256, 0, stream>>>(x, q_w, k_w, v_w, o_w, rel_bias,
                                    xb, wqkv, owb, biasT);

  dim3 g1(4096 / 128, 3072 / 128);
  gemm_qkv<<<g1, 256, 0, stream>>>(xb, wqkv, qkb, vTp);

  dim3 g2(16, 16, 2);
  flash_attn<<<g2, 512, 0, stream>>>(qkb, vTp, biasT, ctxb);

  dim3 g3(4096 / 64, 1024 / 128);
  gemm_out<<<g3, 256, 0, stream>>>(ctxb, owb, (float*)d_out);
}

// Round 11
// 177.201 us; speedup vs baseline: 2.0788x; 2.0788x over previous
//
#include <hip/hip_runtime.h>
#include <stdint.h>

// T5-style attention, MI355X gfx950.
// B=2 S=2048 D=1024 H=16 DK=64, NUM_BUCKETS=32, MAX_DISTANCE=128.
// R22 = R21 with flash __launch_bounds__(512,4) -> (512,2). R21's "4" capped
// the allocator at 64 VGPRs -> 1.2 GB scratch spill per dispatch (WRITE_SIZE
// 803 MB, dur 247us). (512,2) caps at >=128 VGPR; body needs ~100. Split-K
// within block otherwise unchanged: 8 waves, halves merge via LDS epilogue.

typedef unsigned short u16;
typedef __attribute__((ext_vector_type(8))) short short8;
typedef __attribute__((ext_vector_type(4))) float float4v;
typedef __attribute__((ext_vector_type(4))) u16 ushort4v;
typedef __attribute__((ext_vector_type(4))) uint32_t uint4v;

typedef __attribute__((address_space(1))) void void_g;
typedef __attribute__((address_space(3))) void void_l;

#define L2E 1.4426950408889634f

__device__ __forceinline__ u16 f2b(float f) {
  union { float f; uint32_t u; } v; v.f = f;
  uint32_t r = (v.u + 0x7fffu + ((v.u >> 16) & 1u)) >> 16;
  return (u16)r;
}
__device__ __forceinline__ u16 f2b_fast(float f) {
  union { float f; uint32_t u; } v; v.f = f;
  return (u16)((v.u + 0x8000u) >> 16);
}
__device__ __forceinline__ uint32_t cvt_pk_bf16(float lo, float hi) {
  uint32_t r;
  asm("v_cvt_pk_bf16_f32 %0, %1, %2" : "=v"(r) : "v"(lo), "v"(hi));
  return r;
}

// ---------------- fused fp32->bf16 convert + bias table -------------------------
__global__ void cvt_all(const float* __restrict__ x,  const float* __restrict__ qw,
                        const float* __restrict__ kw, const float* __restrict__ vw,
                        const float* __restrict__ ow, const float* __restrict__ rel_bias,
                        u16* __restrict__ xb, u16* __restrict__ wqkv, u16* __restrict__ owb,
                        float* __restrict__ biasT) {
  int bi = blockIdx.x;
  if (bi >= 8192) {
    int idx = (bi - 8192) * 256 + threadIdx.x;   // 0..65535
    int h = idx >> 12, t = idx & 4095;
    if (t > 4094) { biasT[h * 4096 + 4095] = -1.0e4f; return; }
    int d = t - 2047;
    int n = -d;
    int ret = (n < 0) ? 16 : 0;
    int na = (n < 0) ? -n : n;
    int bucket;
    if (na < 8) {
      bucket = ret + na;
    } else {
      float v = logf((float)na / 8.0f) / logf(16.0f) * 8.0f;
      int vi = 8 + (int)v;
      bucket = ret + (vi > 15 ? 15 : vi);
    }
    biasT[h * 4096 + t] = (rel_bias[bucket * 16 + h] - 8.0f) * L2E;
    return;
  }
  int i = bi * 256 + threadIdx.x;
  const float* s; u16* d; int off;
  if (i < 1048576)      { s = x;  d = xb;              off = i; }
  else if (i < 1310720) { s = qw; d = wqkv;            off = i - 1048576; }
  else if (i < 1572864) { s = kw; d = wqkv + 1048576;  off = i - 1310720; }
  else if (i < 1835008) { s = vw; d = wqkv + 2097152;  off = i - 1572864; }
  else                  { s = ow; d = owb;             off = i - 1835008; }
  float4v v = ((const float4v*)s)[off];
  ushort4v o;
  o.x = f2b(v.x); o.y = f2b(v.y); o.z = f2b(v.z); o.w = f2b(v.w);
  ((ushort4v*)d)[off] = o;
}

// ---------------- QKV GEMM: [4096,3072] = xb[4096,1024] * wqkv[3072,1024]^T ----
// 128x128 tile, BK=64, single-buffered LDS (34816 B -> 3 blocks/CU).
// XCD-chunked swizzle. Q/K epilogue via LDS transpose; V epilogue in registers.
__global__ __launch_bounds__(256, 3)
void gemm_qkv(const u16* __restrict__ A, const u16* __restrict__ W,
              u16* __restrict__ qkb, u16* __restrict__ vTp) {
  const int K = 1024;
  __shared__ __align__(16) char SM[34816];
  u16* As = (u16*)SM;            // [kk][row][32]
  u16* Bs = (u16*)(SM + 16384);
  const int tid = threadIdx.x;
  const int wid = tid >> 6;
  const int lane = tid & 63;
  const int row16 = lane & 15, oct = lane >> 4;
  // bijective XCD chunk: 768 blocks, 96 per XCD
  const int lin = blockIdx.x + blockIdx.y * 32;     // grid (32,24) x-major
  const int V = (lin & 7) * 96 + (lin >> 3);
  const int bx = V & 31, by = V >> 5;
  const int tm = bx * 128, tn = by * 128;
  const int wm = (wid & 1) * 64, wn = (wid >> 1) * 64;
  const int srow = lane >> 2;
  const int sc = (lane & 3) * 8;
  float4v acc[4][4] = {};
  for (int k0 = 0; k0 < K; k0 += 64) {
    __syncthreads();
#pragma unroll
    for (int i = 0; i < 4; i++) {
      const int idx = i * 4 + wid;
      const int kk = idx & 1;
      const int rb = idx >> 1;
      const int r = rb * 16 + srow;
      const int c = kk * 32 + sc;
      __builtin_amdgcn_global_load_lds((void_g*)(A + (size_t)(tm + r) * K + k0 + c),
                                       (void_l*)(As + (kk * 128 + rb * 16) * 32), 16, 0, 0);
      __builtin_amdgcn_global_load_lds((void_g*)(W + (size_t)(tn + r) * K + k0 + c),
                                       (void_l*)(Bs + (kk * 128 + rb * 16) * 32), 16, 0, 0);
    }
    __syncthreads();
#pragma unroll
    for (int kk = 0; kk < 2; kk++) {
      short8 af[4], bfr[4];
#pragma unroll
      for (int mi = 0; mi < 4; mi++)
        af[mi] = *(const short8*)(As + (kk * 128 + wm + mi * 16 + row16) * 32 + oct * 8);
#pragma unroll
      for (int ni = 0; ni < 4; ni++)
        bfr[ni] = *(const short8*)(Bs + (kk * 128 + wn + ni * 16 + row16) * 32 + oct * 8);
#pragma unroll
      for (int mi = 0; mi < 4; mi++)
#pragma unroll
        for (int ni = 0; ni < 4; ni++)
          acc[mi][ni] = __builtin_amdgcn_mfma_f32_16x16x32_bf16(af[mi], bfr[ni], acc[mi][ni], 0, 0, 0);
    }
  }

  if (tn < 2048) {
    // Q/K: stage 128x128 bf16 tile in LDS (pitch 136), row-major out
    u16* Es = (u16*)SM;
    __syncthreads();
#pragma unroll
    for (int mi = 0; mi < 4; mi++)
#pragma unroll
      for (int ni = 0; ni < 4; ni++)
#pragma unroll
        for (int r = 0; r < 4; r++)
          Es[(wm + mi * 16 + oct * 4 + r) * 136 + wn + ni * 16 + row16] = f2b(acc[mi][ni][r]);
    __syncthreads();
#pragma unroll
    for (int it = 0; it < 8; it++) {
      int idx = it * 256 + tid;
      int row = idx >> 4, c = idx & 15;
      short8 v = *(const short8*)(Es + row * 136 + c * 8);
      *(short8*)(qkb + (size_t)(tm + row) * 2048 + tn + c * 8) = v;
    }
  } else {
    // V: direct register epilogue. Stored slot u = 8*oct + 4*(mi&1) + r holds
    // acc row; thread stores 8 contiguous bf16 per (bb, ni).
    const int h0 = (tn - 2048) >> 6;
    const int b = tm >> 11;
    const int s0 = tm & 2047;
#pragma unroll
    for (int ni = 0; ni < 4; ni++) {
      const int dg = wn + ni * 16 + row16;
      const int head = h0 + (dg >> 6), d = dg & 63;
      u16* vdst = vTp + ((size_t)((b * 16 + head) * 64 + d)) * 2048 + s0 + wm + oct * 8;
#pragma unroll
      for (int bb = 0; bb < 2; bb++) {
        uint4v pw;
        pw.x = cvt_pk_bf16(acc[2 * bb][ni][0], acc[2 * bb][ni][1]);
        pw.y = cvt_pk_bf16(acc[2 * bb][ni][2], acc[2 * bb][ni][3]);
        pw.z = cvt_pk_bf16(acc[2 * bb + 1][ni][0], acc[2 * bb + 1][ni][1]);
        pw.w = cvt_pk_bf16(acc[2 * bb + 1][ni][2], acc[2 * bb + 1][ni][3]);
        *(uint4v*)(vdst + bb * 32) = pw;
      }
    }
  }
}

// ---------------- out GEMM: d_out[4096,1024] = ctxb * owb^T (f32 out) ----------
// 64x128 tile, grid (64,8)=512 blocks, 2-phase double-buffered LDS.
// Direct-from-register f32 epilogue (row-major out, no transpose needed).
__global__ __launch_bounds__(256, 2)
void gemm_out(const u16* __restrict__ A, const u16* __restrict__ W,
              float* __restrict__ C) {
  const int K = 1024, N = 1024;
  __shared__ __align__(16) char SM[49152];   // [buf][A 8K | B 16K]
  const int tid = threadIdx.x;
  const int wid = tid >> 6;
  const int lane = tid & 63;
  const int row16 = lane & 15, oct = lane >> 4;
  const int tm = blockIdx.x * 64, tn = blockIdx.y * 128;
  const int wm = (wid & 1) * 32, wn = (wid >> 1) * 64;
  const int srow = lane >> 2;
  const int sc = (lane & 3) * 8;
  float4v acc[2][4] = {};

#define STAGE_OUT(buf, k0)                                                            \
  {                                                                                   \
    u16* Ad = (u16*)(SM + (buf) * 24576);                                             \
    u16* Bd = (u16*)(SM + (buf) * 24576 + 8192);                                      \
    _Pragma("unroll")                                                                 \
    for (int i = 0; i < 2; i++) {                                                     \
      const int idx = i * 4 + wid;                                                    \
      const int kk = idx & 1;                                                         \
      const int rb = idx >> 1;                                                        \
      const int r = rb * 16 + srow;                                                   \
      const int c = kk * 32 + sc;                                                     \
      __builtin_amdgcn_global_load_lds((void_g*)(A + (size_t)(tm + r) * K + (k0) + c),\
                                       (void_l*)(Ad + (kk * 64 + rb * 16) * 32), 16, 0, 0); \
    }                                                                                 \
    _Pragma("unroll")                                                                 \
    for (int i = 0; i < 4; i++) {                                                     \
      const int idx = i * 4 + wid;                                                    \
      const int kk = idx & 1;                                                         \
      const int rb = idx >> 1;                                                        \
      const int r = rb * 16 + srow;                                                   \
      const int c = kk * 32 + sc;                                                     \
      __builtin_amdgcn_global_load_lds((void_g*)(W + (size_t)(tn + r) * K + (k0) + c),\
                                       (void_l*)(Bd + (kk * 128 + rb * 16) * 32), 16, 0, 0); \
    }                                                                                 \
  }

  STAGE_OUT(0, 0);
  __syncthreads();
  for (int t = 0; t < 16; t++) {
    if (t + 1 < 16) STAGE_OUT((t + 1) & 1, (t + 1) * 64);
    const u16* As = (const u16*)(SM + (t & 1) * 24576);
    const u16* Bs = As + 4096;   // 8192 bytes
#pragma unroll
    for (int kk = 0; kk < 2; kk++) {
      short8 af[2], bfr[4];
#pragma unroll
      for (int mi = 0; mi < 2; mi++)
        af[mi] = *(const short8*)(As + (kk * 64 + wm + mi * 16 + row16) * 32 + oct * 8);
#pragma unroll
      for (int ni = 0; ni < 4; ni++)
        bfr[ni] = *(const short8*)(Bs + (kk * 128 + wn + ni * 16 + row16) * 32 + oct * 8);
#pragma unroll
      for (int mi = 0; mi < 2; mi++)
#pragma unroll
        for (int ni = 0; ni < 4; ni++)
          acc[mi][ni] = __builtin_amdgcn_mfma_f32_16x16x32_bf16(af[mi], bfr[ni], acc[mi][ni], 0, 0, 0);
    }
    __syncthreads();
  }
  // direct f32 epilogue: row = tm+wm+mi*16+oct*4+r, col = tn+wn+ni*16+row16.
#pragma unroll
  for (int mi = 0; mi < 2; mi++)
#pragma unroll
    for (int ni = 0; ni < 4; ni++)
#pragma unroll
      for (int r = 0; r < 4; r++)
        C[(size_t)(tm + wm + mi * 16 + oct * 4 + r) * N + tn + wn + ni * 16 + row16] =
            acc[mi][ni][r];
}

// ---------------- flash attention (split-K within block) -----------------------
// grid (16,16,2) x 512 threads = 8 waves. Wave w: q-rows (w&3)*32..+32 of the
// 128-row q-tile, KV half (w>>2). Static-max softmax -> (o,l) partials add
// exactly; merged via LDS epilogue. Single-buffered K/V per half, 2 barriers
// per tile. Swapped QK^T, lane-local P pack, ones-MFMA row-sum as R18.
__global__ __launch_bounds__(512, 2)
void flash_attn(const u16* __restrict__ qkb, const u16* __restrict__ vTp,
                const float* __restrict__ biasT, u16* __restrict__ ctx) {
  const int S = 2048, LDQ = 2048;
  const int lin = blockIdx.x + (blockIdx.y << 4) + (blockIdx.z << 8);
  const int V = (lin & 7) * 64 + (lin >> 3);
  const int qt0 = (V & 15) * 128;
  const int h = (V >> 4) & 15, b = V >> 8;
  const int tid = threadIdx.x, wid = tid >> 6, lane = tid & 63;
  const int row16 = lane & 15, oct = lane >> 4;
  const int qw = wid & 3;          // q-row group
  const int half = wid >> 2;       // KV half

  __shared__ __align__(16) char SM[49664];
  float* biasS = (float*)SM;                        // [0, 8704)
  u16* KsB  = (u16*)(SM + 8704);                    // [half][hd][64][40] 20480 B
  u16* VtsB = (u16*)(SM + 8704 + 20480);            // [half][ks][64][40] 20480 B

  {
    const float* bsrc = biasT + h * 4096 + (1920 - qt0);
    for (int i = tid; i < 544; i += 512)
      ((float4v*)biasS)[i] = ((const float4v*)bsrc)[i];
  }
  const float bias_neg = biasT[h * 4096];          // d <= -128 (bucket 15)
  const float bias_pos = biasT[h * 4096 + 4094];   // d >= +128 (bucket 31)

  const u16* qbase = qkb + ((size_t)b * S + qt0 + qw * 32) * LDQ + h * 64;
  short8 qf[2][2];
#pragma unroll
  for (int f = 0; f < 2; f++)
#pragma unroll
    for (int hd = 0; hd < 2; hd++)
      qf[f][hd] = *(const short8*)(qbase + (size_t)(f * 16 + row16) * LDQ + hd * 32 + oct * 8);

  float4v l_acc[2] = {};
  float4v o_acc[2][4] = {};
  const short8 ones = {0x3F80, 0x3F80, 0x3F80, 0x3F80, 0x3F80, 0x3F80, 0x3F80, 0x3F80};

  const int sr = lane >> 2, c8 = (lane & 3) * 8;
  const int srow = qw * 16 + sr;                   // 0..63, staged by 4 waves/half
  const u16* Kst = qkb + 1024 + ((size_t)b * S + half * 1024 + srow) * LDQ + c8 + h * 64;
  const u16* Vst = vTp + ((size_t)(b * 16 + h) * 64 + srow) * 2048 + half * 1024 + c8;

  u16* KsH  = KsB  + half * 2 * 64 * 40;           // this half's K region
  u16* VtsH = VtsB + half * 2 * 64 * 40;           // this half's V region

  short8 kreg[2], vreg[2];
#pragma unroll
  for (int hd = 0; hd < 2; hd++) kreg[hd] = *(const short8*)(Kst + hd * 32);
#pragma unroll
  for (int ks = 0; ks < 2; ks++) vreg[ks] = *(const short8*)(Vst + ks * 32);

  for (int kt = 0; kt < 1024; kt += 64) {
    __syncthreads();
#pragma unroll
    for (int hd = 0; hd < 2; hd++)
      *(short8*)(KsH + (hd * 64 + srow) * 40 + c8) = kreg[hd];
#pragma unroll
    for (int ks = 0; ks < 2; ks++)
      *(short8*)(VtsH + (ks * 64 + srow) * 40 + c8) = vreg[ks];
    __syncthreads();

    if (kt + 64 < 1024) {
#pragma unroll
      for (int hd = 0; hd < 2; hd++)
        kreg[hd] = *(const short8*)(Kst + (size_t)(kt + 64) * LDQ + hd * 32);
#pragma unroll
      for (int ks = 0; ks < 2; ks++)
        vreg[ks] = *(const short8*)(Vst + (kt + 64) + ks * 32);
    }

    short8 kf[4][2];
#pragma unroll
    for (int st = 0; st < 4; st++)
#pragma unroll
      for (int hd = 0; hd < 2; hd++)
        kf[st][hd] = *(const short8*)(KsH + (hd * 64 + st * 16 + row16) * 40 + oct * 8);

    // swapped QK^T: lane holds S[k = st*16 + oct*4 + r][q = row16]
    float4v sc[2][4];
    __builtin_amdgcn_s_setprio(1);
#pragma unroll
    for (int f = 0; f < 2; f++)
#pragma unroll
      for (int st = 0; st < 4; st++) {
        float4v s = {};
        s = __builtin_amdgcn_mfma_f32_16x16x32_bf16(kf[st][0], qf[f][0], s, 0, 0, 0);
        s = __builtin_amdgcn_mfma_f32_16x16x32_bf16(kf[st][1], qf[f][1], s, 0, 0, 0);
        sc[f][st] = s;
      }
    __builtin_amdgcn_s_setprio(0);

    short8 vf[2][4];
#pragma unroll
    for (int ks = 0; ks < 2; ks++)
#pragma unroll
      for (int ni = 0; ni < 4; ni++)
        vf[ks][ni] = *(const short8*)(VtsH + (ks * 64 + ni * 16 + row16) * 40 + oct * 8);

    // bias + exp (q = row16, k = st*16 + oct*4 + r; global kt = half*1024+kt)
    const int dk = half * 1024 + kt - qt0;
    const bool far = (dk >= 256) || (dk <= -192);
    if (far) {
      const float bc = (dk > 0) ? bias_pos : bias_neg;
#pragma unroll
      for (int f = 0; f < 2; f++)
#pragma unroll
        for (int st = 0; st < 4; st++)
#pragma unroll
          for (int r = 0; r < 4; r++)
            sc[f][st][r] = __builtin_amdgcn_exp2f(__builtin_fmaf(sc[f][st][r], L2E, bc));
    } else {
#pragma unroll
      for (int f = 0; f < 2; f++) {
        const int basef = half * 1024 + kt + oct * 4 - qw * 32 - f * 16 - row16 + 127;
#pragma unroll
        for (int st = 0; st < 4; st++)
#pragma unroll
          for (int r = 0; r < 4; r++)
            sc[f][st][r] = __builtin_amdgcn_exp2f(
                __builtin_fmaf(sc[f][st][r], L2E, biasS[basef + st * 16 + r]));
      }
    }

#pragma unroll
    for (int f = 0; f < 2; f++) {
#pragma unroll
      for (int ks = 0; ks < 2; ks++) {
        uint4v pw;
        pw.x = cvt_pk_bf16(sc[f][2 * ks][0], sc[f][2 * ks][1]);
        pw.y = cvt_pk_bf16(sc[f][2 * ks][2], sc[f][2 * ks][3]);
        pw.z = cvt_pk_bf16(sc[f][2 * ks + 1][0], sc[f][2 * ks + 1][1]);
        pw.w = cvt_pk_bf16(sc[f][2 * ks + 1][2], sc[f][2 * ks + 1][3]);
        short8 pf = __builtin_bit_cast(short8, pw);
        __builtin_amdgcn_s_setprio(1);
#pragma unroll
        for (int ni = 0; ni < 4; ni++)
          o_acc[f][ni] = __builtin_amdgcn_mfma_f32_16x16x32_bf16(pf, vf[ks][ni], o_acc[f][ni], 0, 0, 0);
        l_acc[f] = __builtin_amdgcn_mfma_f32_16x16x32_bf16(pf, ones, l_acc[f], 0, 0, 0);
        __builtin_amdgcn_s_setprio(0);
      }
    }
  }

  // ---- merge halves via LDS (40 f32 per lane-slot; 256 slots = 40960 B) ----
  __syncthreads();                        // all compute done; LDS reusable
  float* MRG = (float*)SM;
  const int slot = (qw * 64 + lane) * 40;
  if (half == 1) {
#pragma unroll
    for (int f = 0; f < 2; f++) {
#pragma unroll
      for (int ni = 0; ni < 4; ni++)
        *(float4v*)(MRG + slot + (f * 4 + ni) * 4) = o_acc[f][ni];
      *(float4v*)(MRG + slot + 32 + f * 4) = l_acc[f];
    }
  }
  __syncthreads();
  if (half == 0) {
#pragma unroll
    for (int f = 0; f < 2; f++) {
      float4v lp = *(const float4v*)(MRG + slot + 32 + f * 4);
      float linv[4];
#pragma unroll
      for (int r = 0; r < 4; r++)
        linv[r] = 1.0f / (l_acc[f][r] + lp[r]);
      const size_t orow = (size_t)b * S + qt0 + qw * 32 + f * 16 + oct * 4;
#pragma unroll
      for (int ni = 0; ni < 4; ni++) {
        float4v op = *(const float4v*)(MRG + slot + (f * 4 + ni) * 4);
#pragma unroll
        for (int r = 0; r < 4; r++)
          ctx[(orow + r) * 1024 + h * 64 + ni * 16 + row16] =
              f2b_fast((o_acc[f][ni][r] + op[r]) * linv[r]);
      }
    }
  }
}

// ---------------- host launcher ------------------------------------------------
extern "C" void kernel_launch(void* const* d_in, const int* in_sizes, int n_in,
                              void* d_out, int out_size, void* d_ws, size_t ws_size,
                              hipStream_t stream) {
  const float* x        = (const float*)d_in[0];
  const float* q_w      = (const float*)d_in[1];
  const float* k_w      = (const float*)d_in[2];
  const float* v_w      = (const float*)d_in[3];
  const float* o_w      = (const float*)d_in[4];
  const float* rel_bias = (const float*)d_in[5];

  char* ws = (char*)d_ws;
  u16*   xb    = (u16*)(ws);                         // [0,8M)   x bf16
  u16*   wqkv  = (u16*)(ws + 8388608);               // [8M,14M) qkv weights bf16
  u16*   owb   = (u16*)(ws + 14680064);              // [14M,16M) o_w bf16
  u16*   qkb   = (u16*)(ws + 16777216);              // [16M,32M) Q|K rows, LDC=2048
  u16*   vTp   = (u16*)(ws + 33554432);              // [32M,40M) V^T permuted
  u16*   ctxb  = (u16*)(ws + 41943040);              // [40M,48M) attention out bf16
  float* biasT = (float*)(ws + 50331648);            // [48M..] bias table

  cvt_all<<<8448, 256, 0, stream>>>(x, q_w, k_w, v_w, o_w, rel_bias,
                                    xb, wqkv, owb, biasT);

  dim3 g1(4096 / 128, 3072 / 128);
  gemm_qkv<<<g1, 256, 0, stream>>>(xb, wqkv, qkb, vTp);

  dim3 g2(16, 16, 2);
  flash_attn<<<g2, 512, 0, stream>>>(qkb, vTp, biasT, ctxb);

  dim3 g3(4096 / 64, 1024 / 128);
  gemm_out<<<g3, 256, 0, stream>>>(ctxb, owb, (float*)d_out);
}

// Round 12
// 172.214 us; speedup vs baseline: 2.1390x; 1.0290x over previous
//
#include <hip/hip_runtime.h>
#include <stdint.h>

// T5-style attention, MI355X gfx950.
// B=2 S=2048 D=1024 H=16 DK=64, NUM_BUCKETS=32, MAX_DISTANCE=128.
// R23 = exact restore of R20 (session best, 171.5 us).
// Flash: 4 waves / 128-q-tile, K/V dbuf with ONE barrier/tile, swapped QK^T
// (lane-local P), cvt_pk pack, ones-MFMA row-sum, XCD-chunked swizzle.
// Falsified alternatives: QBLK=64 (R15, LDS traffic scales with waves),
// cross-tile pipeline (R19, VGPR spill), split-K in block (R21/R22, barrier
// granularity + occupancy). gemm_qkv: 128^2 single-buf 3 blocks/CU, V-reg
// epilogue. gemm_out: 64x128 dbuf, direct f32 epilogue.

typedef unsigned short u16;
typedef __attribute__((ext_vector_type(8))) short short8;
typedef __attribute__((ext_vector_type(4))) float float4v;
typedef __attribute__((ext_vector_type(4))) u16 ushort4v;
typedef __attribute__((ext_vector_type(4))) uint32_t uint4v;

typedef __attribute__((address_space(1))) void void_g;
typedef __attribute__((address_space(3))) void void_l;

#define L2E 1.4426950408889634f

__device__ __forceinline__ u16 f2b(float f) {
  union { float f; uint32_t u; } v; v.f = f;
  uint32_t r = (v.u + 0x7fffu + ((v.u >> 16) & 1u)) >> 16;
  return (u16)r;
}
__device__ __forceinline__ u16 f2b_fast(float f) {
  union { float f; uint32_t u; } v; v.f = f;
  return (u16)((v.u + 0x8000u) >> 16);
}
__device__ __forceinline__ uint32_t cvt_pk_bf16(float lo, float hi) {
  uint32_t r;
  asm("v_cvt_pk_bf16_f32 %0, %1, %2" : "=v"(r) : "v"(lo), "v"(hi));
  return r;
}

// ---------------- fused fp32->bf16 convert + bias table -------------------------
__global__ void cvt_all(const float* __restrict__ x,  const float* __restrict__ qw,
                        const float* __restrict__ kw, const float* __restrict__ vw,
                        const float* __restrict__ ow, const float* __restrict__ rel_bias,
                        u16* __restrict__ xb, u16* __restrict__ wqkv, u16* __restrict__ owb,
                        float* __restrict__ biasT) {
  int bi = blockIdx.x;
  if (bi >= 8192) {
    int idx = (bi - 8192) * 256 + threadIdx.x;   // 0..65535
    int h = idx >> 12, t = idx & 4095;
    if (t > 4094) { biasT[h * 4096 + 4095] = -1.0e4f; return; }
    int d = t - 2047;
    int n = -d;
    int ret = (n < 0) ? 16 : 0;
    int na = (n < 0) ? -n : n;
    int bucket;
    if (na < 8) {
      bucket = ret + na;
    } else {
      float v = logf((float)na / 8.0f) / logf(16.0f) * 8.0f;
      int vi = 8 + (int)v;
      bucket = ret + (vi > 15 ? 15 : vi);
    }
    biasT[h * 4096 + t] = (rel_bias[bucket * 16 + h] - 8.0f) * L2E;
    return;
  }
  int i = bi * 256 + threadIdx.x;
  const float* s; u16* d; int off;
  if (i < 1048576)      { s = x;  d = xb;              off = i; }
  else if (i < 1310720) { s = qw; d = wqkv;            off = i - 1048576; }
  else if (i < 1572864) { s = kw; d = wqkv + 1048576;  off = i - 1310720; }
  else if (i < 1835008) { s = vw; d = wqkv + 2097152;  off = i - 1572864; }
  else                  { s = ow; d = owb;             off = i - 1835008; }
  float4v v = ((const float4v*)s)[off];
  ushort4v o;
  o.x = f2b(v.x); o.y = f2b(v.y); o.z = f2b(v.z); o.w = f2b(v.w);
  ((ushort4v*)d)[off] = o;
}

// ---------------- QKV GEMM: [4096,3072] = xb[4096,1024] * wqkv[3072,1024]^T ----
// 128x128 tile, BK=64, single-buffered LDS (34816 B -> 3 blocks/CU).
// XCD-chunked swizzle. Q/K epilogue via LDS transpose; V epilogue in registers.
__global__ __launch_bounds__(256, 3)
void gemm_qkv(const u16* __restrict__ A, const u16* __restrict__ W,
              u16* __restrict__ qkb, u16* __restrict__ vTp) {
  const int K = 1024;
  __shared__ __align__(16) char SM[34816];
  u16* As = (u16*)SM;            // [kk][row][32]
  u16* Bs = (u16*)(SM + 16384);
  const int tid = threadIdx.x;
  const int wid = tid >> 6;
  const int lane = tid & 63;
  const int row16 = lane & 15, oct = lane >> 4;
  // bijective XCD chunk: 768 blocks, 96 per XCD
  const int lin = blockIdx.x + blockIdx.y * 32;     // grid (32,24) x-major
  const int V = (lin & 7) * 96 + (lin >> 3);
  const int bx = V & 31, by = V >> 5;
  const int tm = bx * 128, tn = by * 128;
  const int wm = (wid & 1) * 64, wn = (wid >> 1) * 64;
  const int srow = lane >> 2;
  const int sc = (lane & 3) * 8;
  float4v acc[4][4] = {};
  for (int k0 = 0; k0 < K; k0 += 64) {
    __syncthreads();
#pragma unroll
    for (int i = 0; i < 4; i++) {
      const int idx = i * 4 + wid;
      const int kk = idx & 1;
      const int rb = idx >> 1;
      const int r = rb * 16 + srow;
      const int c = kk * 32 + sc;
      __builtin_amdgcn_global_load_lds((void_g*)(A + (size_t)(tm + r) * K + k0 + c),
                                       (void_l*)(As + (kk * 128 + rb * 16) * 32), 16, 0, 0);
      __builtin_amdgcn_global_load_lds((void_g*)(W + (size_t)(tn + r) * K + k0 + c),
                                       (void_l*)(Bs + (kk * 128 + rb * 16) * 32), 16, 0, 0);
    }
    __syncthreads();
#pragma unroll
    for (int kk = 0; kk < 2; kk++) {
      short8 af[4], bfr[4];
#pragma unroll
      for (int mi = 0; mi < 4; mi++)
        af[mi] = *(const short8*)(As + (kk * 128 + wm + mi * 16 + row16) * 32 + oct * 8);
#pragma unroll
      for (int ni = 0; ni < 4; ni++)
        bfr[ni] = *(const short8*)(Bs + (kk * 128 + wn + ni * 16 + row16) * 32 + oct * 8);
#pragma unroll
      for (int mi = 0; mi < 4; mi++)
#pragma unroll
        for (int ni = 0; ni < 4; ni++)
          acc[mi][ni] = __builtin_amdgcn_mfma_f32_16x16x32_bf16(af[mi], bfr[ni], acc[mi][ni], 0, 0, 0);
    }
  }

  if (tn < 2048) {
    // Q/K: stage 128x128 bf16 tile in LDS (pitch 136), row-major out
    u16* Es = (u16*)SM;
    __syncthreads();
#pragma unroll
    for (int mi = 0; mi < 4; mi++)
#pragma unroll
      for (int ni = 0; ni < 4; ni++)
#pragma unroll
        for (int r = 0; r < 4; r++)
          Es[(wm + mi * 16 + oct * 4 + r) * 136 + wn + ni * 16 + row16] = f2b(acc[mi][ni][r]);
    __syncthreads();
#pragma unroll
    for (int it = 0; it < 8; it++) {
      int idx = it * 256 + tid;
      int row = idx >> 4, c = idx & 15;
      short8 v = *(const short8*)(Es + row * 136 + c * 8);
      *(short8*)(qkb + (size_t)(tm + row) * 2048 + tn + c * 8) = v;
    }
  } else {
    // V: direct register epilogue. Stored slot u = 8*oct + 4*(mi&1) + r holds
    // acc row; thread stores 8 contiguous bf16 per (bb, ni).
    const int h0 = (tn - 2048) >> 6;
    const int b = tm >> 11;
    const int s0 = tm & 2047;
#pragma unroll
    for (int ni = 0; ni < 4; ni++) {
      const int dg = wn + ni * 16 + row16;
      const int head = h0 + (dg >> 6), d = dg & 63;
      u16* vdst = vTp + ((size_t)((b * 16 + head) * 64 + d)) * 2048 + s0 + wm + oct * 8;
#pragma unroll
      for (int bb = 0; bb < 2; bb++) {
        uint4v pw;
        pw.x = cvt_pk_bf16(acc[2 * bb][ni][0], acc[2 * bb][ni][1]);
        pw.y = cvt_pk_bf16(acc[2 * bb][ni][2], acc[2 * bb][ni][3]);
        pw.z = cvt_pk_bf16(acc[2 * bb + 1][ni][0], acc[2 * bb + 1][ni][1]);
        pw.w = cvt_pk_bf16(acc[2 * bb + 1][ni][2], acc[2 * bb + 1][ni][3]);
        *(uint4v*)(vdst + bb * 32) = pw;
      }
    }
  }
}

// ---------------- out GEMM: d_out[4096,1024] = ctxb * owb^T (f32 out) ----------
// 64x128 tile, grid (64,8)=512 blocks, 2-phase double-buffered LDS.
// Direct-from-register f32 epilogue (row-major out, no transpose needed).
__global__ __launch_bounds__(256, 2)
void gemm_out(const u16* __restrict__ A, const u16* __restrict__ W,
              float* __restrict__ C) {
  const int K = 1024, N = 1024;
  __shared__ __align__(16) char SM[49152];   // [buf][A 8K | B 16K]
  const int tid = threadIdx.x;
  const int wid = tid >> 6;
  const int lane = tid & 63;
  const int row16 = lane & 15, oct = lane >> 4;
  const int tm = blockIdx.x * 64, tn = blockIdx.y * 128;
  const int wm = (wid & 1) * 32, wn = (wid >> 1) * 64;
  const int srow = lane >> 2;
  const int sc = (lane & 3) * 8;
  float4v acc[2][4] = {};

#define STAGE_OUT(buf, k0)                                                            \
  {                                                                                   \
    u16* Ad = (u16*)(SM + (buf) * 24576);                                             \
    u16* Bd = (u16*)(SM + (buf) * 24576 + 8192);                                      \
    _Pragma("unroll")                                                                 \
    for (int i = 0; i < 2; i++) {                                                     \
      const int idx = i * 4 + wid;                                                    \
      const int kk = idx & 1;                                                         \
      const int rb = idx >> 1;                                                        \
      const int r = rb * 16 + srow;                                                   \
      const int c = kk * 32 + sc;                                                     \
      __builtin_amdgcn_global_load_lds((void_g*)(A + (size_t)(tm + r) * K + (k0) + c),\
                                       (void_l*)(Ad + (kk * 64 + rb * 16) * 32), 16, 0, 0); \
    }                                                                                 \
    _Pragma("unroll")                                                                 \
    for (int i = 0; i < 4; i++) {                                                     \
      const int idx = i * 4 + wid;                                                    \
      const int kk = idx & 1;                                                         \
      const int rb = idx >> 1;                                                        \
      const int r = rb * 16 + srow;                                                   \
      const int c = kk * 32 + sc;                                                     \
      __builtin_amdgcn_global_load_lds((void_g*)(W + (size_t)(tn + r) * K + (k0) + c),\
                                       (void_l*)(Bd + (kk * 128 + rb * 16) * 32), 16, 0, 0); \
    }                                                                                 \
  }

  STAGE_OUT(0, 0);
  __syncthreads();
  for (int t = 0; t < 16; t++) {
    if (t + 1 < 16) STAGE_OUT((t + 1) & 1, (t + 1) * 64);
    const u16* As = (const u16*)(SM + (t & 1) * 24576);
    const u16* Bs = As + 4096;   // 8192 bytes
#pragma unroll
    for (int kk = 0; kk < 2; kk++) {
      short8 af[2], bfr[4];
#pragma unroll
      for (int mi = 0; mi < 2; mi++)
        af[mi] = *(const short8*)(As + (kk * 64 + wm + mi * 16 + row16) * 32 + oct * 8);
#pragma unroll
      for (int ni = 0; ni < 4; ni++)
        bfr[ni] = *(const short8*)(Bs + (kk * 128 + wn + ni * 16 + row16) * 32 + oct * 8);
#pragma unroll
      for (int mi = 0; mi < 2; mi++)
#pragma unroll
        for (int ni = 0; ni < 4; ni++)
          acc[mi][ni] = __builtin_amdgcn_mfma_f32_16x16x32_bf16(af[mi], bfr[ni], acc[mi][ni], 0, 0, 0);
    }
    __syncthreads();
  }
  // direct f32 epilogue: row = tm+wm+mi*16+oct*4+r, col = tn+wn+ni*16+row16.
#pragma unroll
  for (int mi = 0; mi < 2; mi++)
#pragma unroll
    for (int ni = 0; ni < 4; ni++)
#pragma unroll
      for (int r = 0; r < 4; r++)
        C[(size_t)(tm + wm + mi * 16 + oct * 4 + r) * N + tn + wn + ni * 16 + row16] =
            acc[mi][ni][r];
}

// ---------------- flash attention ----------------------------------------------
// grid (S/128, H, B) with XCD-chunked swizzle; block 256 = 4 waves; wave owns
// 32 q-rows. KT=64, K/V double-buffered LDS, ONE barrier per tile:
// write(nb) || compute(cur) -> barrier.
// Swapped QK^T: lane holds P[q=row16][k=st*16+oct*4+r]; PV A-frag packed
// lane-locally via v_cvt_pk_bf16_f32; row-sum l via ones-MFMA in o_acc layout.
__global__ __launch_bounds__(256, 2)
void flash_attn(const u16* __restrict__ qkb, const u16* __restrict__ vTp,
                const float* __restrict__ biasT, u16* __restrict__ ctx) {
  const int S = 2048, LDQ = 2048;
  // XCD-chunked bijection: 512 blocks, 8 XCDs, 64 blocks/XCD.
  const int lin = blockIdx.x + (blockIdx.y << 4) + (blockIdx.z << 8);
  const int V = (lin & 7) * 64 + (lin >> 3);
  const int qt0 = (V & 15) * 128;
  const int h = (V >> 4) & 15, b = V >> 8;
  const int tid = threadIdx.x, wid = tid >> 6, lane = tid & 63;
  const int row16 = lane & 15, oct = lane >> 4;

  __shared__ __align__(16) float biasS[2176];
  __shared__ __align__(16) u16 Ks[2][2][64][40];   // [buf][d-half][k-row][pitch]
  __shared__ __align__(16) u16 Vts[2][2][64][40];  // [buf][ks][d][pitch]

  {
    const float* bsrc = biasT + h * 4096 + (1920 - qt0);
    for (int i = tid; i < 544; i += 256)
      ((float4v*)biasS)[i] = ((const float4v*)bsrc)[i];
  }
  const float bias_neg = biasT[h * 4096];          // d <= -128 (bucket 15)
  const float bias_pos = biasT[h * 4096 + 4094];   // d >= +128 (bucket 31)

  const u16* qbase = qkb + ((size_t)b * S + qt0 + wid * 32) * LDQ + h * 64;
  short8 qf[2][2];
#pragma unroll
  for (int f = 0; f < 2; f++)
#pragma unroll
    for (int hd = 0; hd < 2; hd++)
      qf[f][hd] = *(const short8*)(qbase + (size_t)(f * 16 + row16) * LDQ + hd * 32 + oct * 8);

  float4v l_acc[2] = {};
  float4v o_acc[2][4] = {};
  const short8 ones = {0x3F80, 0x3F80, 0x3F80, 0x3F80, 0x3F80, 0x3F80, 0x3F80, 0x3F80};

  const int sr = lane >> 2, c8 = (lane & 3) * 8;
  const int srow = wid * 16 + sr;
  const u16* Kst = qkb + 1024 + ((size_t)b * S + srow) * LDQ + c8 + h * 64;
  const u16* Vst = vTp + ((size_t)(b * 16 + h) * 64 + srow) * 2048 + c8;

  short8 kreg[2], vreg[2];
  // prologue: stage tile 0 into buf0, load tile 1 into regs, barrier
#pragma unroll
  for (int hd = 0; hd < 2; hd++) kreg[hd] = *(const short8*)(Kst + hd * 32);
#pragma unroll
  for (int ks = 0; ks < 2; ks++) vreg[ks] = *(const short8*)(Vst + ks * 32);
#pragma unroll
  for (int hd = 0; hd < 2; hd++) *(short8*)&Ks[0][hd][srow][c8] = kreg[hd];
#pragma unroll
  for (int ks = 0; ks < 2; ks++) *(short8*)&Vts[0][ks][srow][c8] = vreg[ks];
#pragma unroll
  for (int hd = 0; hd < 2; hd++) kreg[hd] = *(const short8*)(Kst + (size_t)64 * LDQ + hd * 32);
#pragma unroll
  for (int ks = 0; ks < 2; ks++) vreg[ks] = *(const short8*)(Vst + 64 + ks * 32);
  __syncthreads();

  for (int kt = 0; kt < S; kt += 64) {
    const int cur = (kt >> 6) & 1, nb = cur ^ 1;
    // write next tile into other buffer (no barrier needed: nb's last readers
    // finished before the barrier that ended the previous iteration)
    if (kt + 64 < S) {
#pragma unroll
      for (int hd = 0; hd < 2; hd++) *(short8*)&Ks[nb][hd][srow][c8] = kreg[hd];
#pragma unroll
      for (int ks = 0; ks < 2; ks++) *(short8*)&Vts[nb][ks][srow][c8] = vreg[ks];
    }
    // prefetch tile kt+128 into regs (hidden under compute)
    if (kt + 128 < S) {
#pragma unroll
      for (int hd = 0; hd < 2; hd++)
        kreg[hd] = *(const short8*)(Kst + (size_t)(kt + 128) * LDQ + hd * 32);
#pragma unroll
      for (int ks = 0; ks < 2; ks++)
        vreg[ks] = *(const short8*)(Vst + (kt + 128) + ks * 32);
    }

    short8 kf[4][2];
#pragma unroll
    for (int st = 0; st < 4; st++)
#pragma unroll
      for (int hd = 0; hd < 2; hd++)
        kf[st][hd] = *(const short8*)&Ks[cur][hd][st * 16 + row16][oct * 8];

    // swapped QK^T: lane holds S[k = st*16 + oct*4 + r][q = row16]
    float4v sc[2][4];
    __builtin_amdgcn_s_setprio(1);
#pragma unroll
    for (int f = 0; f < 2; f++)
#pragma unroll
      for (int st = 0; st < 4; st++) {
        float4v s = {};
        s = __builtin_amdgcn_mfma_f32_16x16x32_bf16(kf[st][0], qf[f][0], s, 0, 0, 0);
        s = __builtin_amdgcn_mfma_f32_16x16x32_bf16(kf[st][1], qf[f][1], s, 0, 0, 0);
        sc[f][st] = s;
      }
    __builtin_amdgcn_s_setprio(0);

    short8 vf[2][4];
#pragma unroll
    for (int ks = 0; ks < 2; ks++)
#pragma unroll
      for (int ni = 0; ni < 4; ni++)
        vf[ks][ni] = *(const short8*)&Vts[cur][ks][ni * 16 + row16][oct * 8];

    // bias + exp (swapped layout: q = row16, k = st*16 + oct*4 + r)
    const int dk = kt - qt0;
    const bool far = (dk >= 256) || (dk <= -192);
    if (far) {
      const float bc = (dk > 0) ? bias_pos : bias_neg;
#pragma unroll
      for (int f = 0; f < 2; f++)
#pragma unroll
        for (int st = 0; st < 4; st++)
#pragma unroll
          for (int r = 0; r < 4; r++)
            sc[f][st][r] = __builtin_amdgcn_exp2f(__builtin_fmaf(sc[f][st][r], L2E, bc));
    } else {
#pragma unroll
      for (int f = 0; f < 2; f++) {
        const int basef = kt + oct * 4 - wid * 32 - f * 16 - row16 + 127;
#pragma unroll
        for (int st = 0; st < 4; st++)
#pragma unroll
          for (int r = 0; r < 4; r++)
            sc[f][st][r] = __builtin_amdgcn_exp2f(
                __builtin_fmaf(sc[f][st][r], L2E, biasS[basef + st * 16 + r]));
      }
    }

#pragma unroll
    for (int f = 0; f < 2; f++) {
      // lane-local P pack -> PV A-fragment (kk slot j: st = 2ks + (j>=4), r = j&3)
#pragma unroll
      for (int ks = 0; ks < 2; ks++) {
        uint4v pw;
        pw.x = cvt_pk_bf16(sc[f][2 * ks][0], sc[f][2 * ks][1]);
        pw.y = cvt_pk_bf16(sc[f][2 * ks][2], sc[f][2 * ks][3]);
        pw.z = cvt_pk_bf16(sc[f][2 * ks + 1][0], sc[f][2 * ks + 1][1]);
        pw.w = cvt_pk_bf16(sc[f][2 * ks + 1][2], sc[f][2 * ks + 1][3]);
        short8 pf = __builtin_bit_cast(short8, pw);
        __builtin_amdgcn_s_setprio(1);
#pragma unroll
        for (int ni = 0; ni < 4; ni++)
          o_acc[f][ni] = __builtin_amdgcn_mfma_f32_16x16x32_bf16(pf, vf[ks][ni], o_acc[f][ni], 0, 0, 0);
        // row-sum: D[q][*] += sum_k P[q][k]  (B = 1.0) -- same layout as o_acc
        l_acc[f] = __builtin_amdgcn_mfma_f32_16x16x32_bf16(pf, ones, l_acc[f], 0, 0, 0);
        __builtin_amdgcn_s_setprio(0);
      }
    }
    __syncthreads();
  }

  // epilogue: l_acc[f][r] is the row-sum for q = ... + oct*4 + r (o_acc rows)
#pragma unroll
  for (int f = 0; f < 2; f++) {
    float linv[4];
#pragma unroll
    for (int r = 0; r < 4; r++)
      linv[r] = 1.0f / l_acc[f][r];
    const size_t orow = (size_t)b * S + qt0 + wid * 32 + f * 16 + oct * 4;
#pragma unroll
    for (int ni = 0; ni < 4; ni++)
#pragma unroll
      for (int r = 0; r < 4; r++)
        ctx[(orow + r) * 1024 + h * 64 + ni * 16 + row16] = f2b_fast(o_acc[f][ni][r] * linv[r]);
  }
}

// ---------------- host launcher ------------------------------------------------
extern "C" void kernel_launch(void* const* d_in, const int* in_sizes, int n_in,
                              void* d_out, int out_size, void* d_ws, size_t ws_size,
                              hipStream_t stream) {
  const float* x        = (const float*)d_in[0];
  const float* q_w      = (const float*)d_in[1];
  const float* k_w      = (const float*)d_in[2];
  const float* v_w      = (const float*)d_in[3];
  const float* o_w      = (const float*)d_in[4];
  const float* rel_bias = (const float*)d_in[5];

  char* ws = (char*)d_ws;
  u16*   xb    = (u16*)(ws);                         // [0,8M)   x bf16
  u16*   wqkv  = (u16*)(ws + 8388608);               // [8M,14M) qkv weights bf16
  u16*   owb   = (u16*)(ws + 14680064);              // [14M,16M) o_w bf16
  u16*   qkb   = (u16*)(ws + 16777216);              // [16M,32M) Q|K rows, LDC=2048
  u16*   vTp   = (u16*)(ws + 33554432);              // [32M,40M) V^T permuted
  u16*   ctxb  = (u16*)(ws + 41943040);              // [40M,48M) attention out bf16
  float* biasT = (float*)(ws + 50331648);            // [48M..] bias table

  cvt_all<<<8448, 256, 0, stream>>>(x, q_w, k_w, v_w, o_w, rel_bias,
                                    xb, wqkv, owb, biasT);

  dim3 g1(4096 / 128, 3072 / 128);
  gemm_qkv<<<g1, 256, 0, stream>>>(xb, wqkv, qkb, vTp);

  dim3 g2(2048 / 128, 16, 2);
  flash_attn<<<g2, 256, 0, stream>>>(qkb, vTp, biasT, ctxb);

  dim3 g3(4096 / 64, 1024 / 128);
  gemm_out<<<g3, 256, 0, stream>>>(ctxb, owb, (float*)d_out);
}

// Round 13
// 170.659 us; speedup vs baseline: 2.1585x; 1.0091x over previous
//
#include <hip/hip_runtime.h>
#include <stdint.h>

// T5-style attention, MI355X gfx950.
// B=2 S=2048 D=1024 H=16 DK=64, NUM_BUCKETS=32, MAX_DISTANCE=128.
// R24 = R23 (= R20, session best 171.5us) with ONE change: flash main-loop
// barrier __syncthreads() -> {s_waitcnt lgkmcnt(0); s_barrier; sched_barrier}.
// Rationale: __syncthreads drains vmcnt(0), syncing all waves to the slowest
// t+2 register prefetch; the barrier's real dependency is LDS-only (ds_write
// of buf nb before other waves read it). Global prefetch loads are private
// registers -- compiler auto-inserts counted vmcnt before their use (T4
// pattern, m201 precedent). gemm kernels unchanged (their staging is
// global_load_lds -> vmcnt at barrier semantically required; m139 null).

typedef unsigned short u16;
typedef __attribute__((ext_vector_type(8))) short short8;
typedef __attribute__((ext_vector_type(4))) float float4v;
typedef __attribute__((ext_vector_type(4))) u16 ushort4v;
typedef __attribute__((ext_vector_type(4))) uint32_t uint4v;

typedef __attribute__((address_space(1))) void void_g;
typedef __attribute__((address_space(3))) void void_l;

#define L2E 1.4426950408889634f

__device__ __forceinline__ u16 f2b(float f) {
  union { float f; uint32_t u; } v; v.f = f;
  uint32_t r = (v.u + 0x7fffu + ((v.u >> 16) & 1u)) >> 16;
  return (u16)r;
}
__device__ __forceinline__ u16 f2b_fast(float f) {
  union { float f; uint32_t u; } v; v.f = f;
  return (u16)((v.u + 0x8000u) >> 16);
}
__device__ __forceinline__ uint32_t cvt_pk_bf16(float lo, float hi) {
  uint32_t r;
  asm("v_cvt_pk_bf16_f32 %0, %1, %2" : "=v"(r) : "v"(lo), "v"(hi));
  return r;
}

// ---------------- fused fp32->bf16 convert + bias table -------------------------
__global__ void cvt_all(const float* __restrict__ x,  const float* __restrict__ qw,
                        const float* __restrict__ kw, const float* __restrict__ vw,
                        const float* __restrict__ ow, const float* __restrict__ rel_bias,
                        u16* __restrict__ xb, u16* __restrict__ wqkv, u16* __restrict__ owb,
                        float* __restrict__ biasT) {
  int bi = blockIdx.x;
  if (bi >= 8192) {
    int idx = (bi - 8192) * 256 + threadIdx.x;   // 0..65535
    int h = idx >> 12, t = idx & 4095;
    if (t > 4094) { biasT[h * 4096 + 4095] = -1.0e4f; return; }
    int d = t - 2047;
    int n = -d;
    int ret = (n < 0) ? 16 : 0;
    int na = (n < 0) ? -n : n;
    int bucket;
    if (na < 8) {
      bucket = ret + na;
    } else {
      float v = logf((float)na / 8.0f) / logf(16.0f) * 8.0f;
      int vi = 8 + (int)v;
      bucket = ret + (vi > 15 ? 15 : vi);
    }
    biasT[h * 4096 + t] = (rel_bias[bucket * 16 + h] - 8.0f) * L2E;
    return;
  }
  int i = bi * 256 + threadIdx.x;
  const float* s; u16* d; int off;
  if (i < 1048576)      { s = x;  d = xb;              off = i; }
  else if (i < 1310720) { s = qw; d = wqkv;            off = i - 1048576; }
  else if (i < 1572864) { s = kw; d = wqkv + 1048576;  off = i - 1310720; }
  else if (i < 1835008) { s = vw; d = wqkv + 2097152;  off = i - 1572864; }
  else                  { s = ow; d = owb;             off = i - 1835008; }
  float4v v = ((const float4v*)s)[off];
  ushort4v o;
  o.x = f2b(v.x); o.y = f2b(v.y); o.z = f2b(v.z); o.w = f2b(v.w);
  ((ushort4v*)d)[off] = o;
}

// ---------------- QKV GEMM: [4096,3072] = xb[4096,1024] * wqkv[3072,1024]^T ----
// 128x128 tile, BK=64, single-buffered LDS (34816 B -> 3 blocks/CU).
// XCD-chunked swizzle. Q/K epilogue via LDS transpose; V epilogue in registers.
__global__ __launch_bounds__(256, 3)
void gemm_qkv(const u16* __restrict__ A, const u16* __restrict__ W,
              u16* __restrict__ qkb, u16* __restrict__ vTp) {
  const int K = 1024;
  __shared__ __align__(16) char SM[34816];
  u16* As = (u16*)SM;            // [kk][row][32]
  u16* Bs = (u16*)(SM + 16384);
  const int tid = threadIdx.x;
  const int wid = tid >> 6;
  const int lane = tid & 63;
  const int row16 = lane & 15, oct = lane >> 4;
  // bijective XCD chunk: 768 blocks, 96 per XCD
  const int lin = blockIdx.x + blockIdx.y * 32;     // grid (32,24) x-major
  const int V = (lin & 7) * 96 + (lin >> 3);
  const int bx = V & 31, by = V >> 5;
  const int tm = bx * 128, tn = by * 128;
  const int wm = (wid & 1) * 64, wn = (wid >> 1) * 64;
  const int srow = lane >> 2;
  const int sc = (lane & 3) * 8;
  float4v acc[4][4] = {};
  for (int k0 = 0; k0 < K; k0 += 64) {
    __syncthreads();
#pragma unroll
    for (int i = 0; i < 4; i++) {
      const int idx = i * 4 + wid;
      const int kk = idx & 1;
      const int rb = idx >> 1;
      const int r = rb * 16 + srow;
      const int c = kk * 32 + sc;
      __builtin_amdgcn_global_load_lds((void_g*)(A + (size_t)(tm + r) * K + k0 + c),
                                       (void_l*)(As + (kk * 128 + rb * 16) * 32), 16, 0, 0);
      __builtin_amdgcn_global_load_lds((void_g*)(W + (size_t)(tn + r) * K + k0 + c),
                                       (void_l*)(Bs + (kk * 128 + rb * 16) * 32), 16, 0, 0);
    }
    __syncthreads();
#pragma unroll
    for (int kk = 0; kk < 2; kk++) {
      short8 af[4], bfr[4];
#pragma unroll
      for (int mi = 0; mi < 4; mi++)
        af[mi] = *(const short8*)(As + (kk * 128 + wm + mi * 16 + row16) * 32 + oct * 8);
#pragma unroll
      for (int ni = 0; ni < 4; ni++)
        bfr[ni] = *(const short8*)(Bs + (kk * 128 + wn + ni * 16 + row16) * 32 + oct * 8);
#pragma unroll
      for (int mi = 0; mi < 4; mi++)
#pragma unroll
        for (int ni = 0; ni < 4; ni++)
          acc[mi][ni] = __builtin_amdgcn_mfma_f32_16x16x32_bf16(af[mi], bfr[ni], acc[mi][ni], 0, 0, 0);
    }
  }

  if (tn < 2048) {
    // Q/K: stage 128x128 bf16 tile in LDS (pitch 136), row-major out
    u16* Es = (u16*)SM;
    __syncthreads();
#pragma unroll
    for (int mi = 0; mi < 4; mi++)
#pragma unroll
      for (int ni = 0; ni < 4; ni++)
#pragma unroll
        for (int r = 0; r < 4; r++)
          Es[(wm + mi * 16 + oct * 4 + r) * 136 + wn + ni * 16 + row16] = f2b(acc[mi][ni][r]);
    __syncthreads();
#pragma unroll
    for (int it = 0; it < 8; it++) {
      int idx = it * 256 + tid;
      int row = idx >> 4, c = idx & 15;
      short8 v = *(const short8*)(Es + row * 136 + c * 8);
      *(short8*)(qkb + (size_t)(tm + row) * 2048 + tn + c * 8) = v;
    }
  } else {
    // V: direct register epilogue. Stored slot u = 8*oct + 4*(mi&1) + r holds
    // acc row; thread stores 8 contiguous bf16 per (bb, ni).
    const int h0 = (tn - 2048) >> 6;
    const int b = tm >> 11;
    const int s0 = tm & 2047;
#pragma unroll
    for (int ni = 0; ni < 4; ni++) {
      const int dg = wn + ni * 16 + row16;
      const int head = h0 + (dg >> 6), d = dg & 63;
      u16* vdst = vTp + ((size_t)((b * 16 + head) * 64 + d)) * 2048 + s0 + wm + oct * 8;
#pragma unroll
      for (int bb = 0; bb < 2; bb++) {
        uint4v pw;
        pw.x = cvt_pk_bf16(acc[2 * bb][ni][0], acc[2 * bb][ni][1]);
        pw.y = cvt_pk_bf16(acc[2 * bb][ni][2], acc[2 * bb][ni][3]);
        pw.z = cvt_pk_bf16(acc[2 * bb + 1][ni][0], acc[2 * bb + 1][ni][1]);
        pw.w = cvt_pk_bf16(acc[2 * bb + 1][ni][2], acc[2 * bb + 1][ni][3]);
        *(uint4v*)(vdst + bb * 32) = pw;
      }
    }
  }
}

// ---------------- out GEMM: d_out[4096,1024] = ctxb * owb^T (f32 out) ----------
// 64x128 tile, grid (64,8)=512 blocks, 2-phase double-buffered LDS.
// Direct-from-register f32 epilogue (row-major out, no transpose needed).
__global__ __launch_bounds__(256, 2)
void gemm_out(const u16* __restrict__ A, const u16* __restrict__ W,
              float* __restrict__ C) {
  const int K = 1024, N = 1024;
  __shared__ __align__(16) char SM[49152];   // [buf][A 8K | B 16K]
  const int tid = threadIdx.x;
  const int wid = tid >> 6;
  const int lane = tid & 63;
  const int row16 = lane & 15, oct = lane >> 4;
  const int tm = blockIdx.x * 64, tn = blockIdx.y * 128;
  const int wm = (wid & 1) * 32, wn = (wid >> 1) * 64;
  const int srow = lane >> 2;
  const int sc = (lane & 3) * 8;
  float4v acc[2][4] = {};

#define STAGE_OUT(buf, k0)                                                            \
  {                                                                                   \
    u16* Ad = (u16*)(SM + (buf) * 24576);                                             \
    u16* Bd = (u16*)(SM + (buf) * 24576 + 8192);                                      \
    _Pragma("unroll")                                                                 \
    for (int i = 0; i < 2; i++) {                                                     \
      const int idx = i * 4 + wid;                                                    \
      const int kk = idx & 1;                                                         \
      const int rb = idx >> 1;                                                        \
      const int r = rb * 16 + srow;                                                   \
      const int c = kk * 32 + sc;                                                     \
      __builtin_amdgcn_global_load_lds((void_g*)(A + (size_t)(tm + r) * K + (k0) + c),\
                                       (void_l*)(Ad + (kk * 64 + rb * 16) * 32), 16, 0, 0); \
    }                                                                                 \
    _Pragma("unroll")                                                                 \
    for (int i = 0; i < 4; i++) {                                                     \
      const int idx = i * 4 + wid;                                                    \
      const int kk = idx & 1;                                                         \
      const int rb = idx >> 1;                                                        \
      const int r = rb * 16 + srow;                                                   \
      const int c = kk * 32 + sc;                                                     \
      __builtin_amdgcn_global_load_lds((void_g*)(W + (size_t)(tn + r) * K + (k0) + c),\
                                       (void_l*)(Bd + (kk * 128 + rb * 16) * 32), 16, 0, 0); \
    }                                                                                 \
  }

  STAGE_OUT(0, 0);
  __syncthreads();
  for (int t = 0; t < 16; t++) {
    if (t + 1 < 16) STAGE_OUT((t + 1) & 1, (t + 1) * 64);
    const u16* As = (const u16*)(SM + (t & 1) * 24576);
    const u16* Bs = As + 4096;   // 8192 bytes
#pragma unroll
    for (int kk = 0; kk < 2; kk++) {
      short8 af[2], bfr[4];
#pragma unroll
      for (int mi = 0; mi < 2; mi++)
        af[mi] = *(const short8*)(As + (kk * 64 + wm + mi * 16 + row16) * 32 + oct * 8);
#pragma unroll
      for (int ni = 0; ni < 4; ni++)
        bfr[ni] = *(const short8*)(Bs + (kk * 128 + wn + ni * 16 + row16) * 32 + oct * 8);
#pragma unroll
      for (int mi = 0; mi < 2; mi++)
#pragma unroll
        for (int ni = 0; ni < 4; ni++)
          acc[mi][ni] = __builtin_amdgcn_mfma_f32_16x16x32_bf16(af[mi], bfr[ni], acc[mi][ni], 0, 0, 0);
    }
    __syncthreads();
  }
  // direct f32 epilogue: row = tm+wm+mi*16+oct*4+r, col = tn+wn+ni*16+row16.
#pragma unroll
  for (int mi = 0; mi < 2; mi++)
#pragma unroll
    for (int ni = 0; ni < 4; ni++)
#pragma unroll
      for (int r = 0; r < 4; r++)
        C[(size_t)(tm + wm + mi * 16 + oct * 4 + r) * N + tn + wn + ni * 16 + row16] =
            acc[mi][ni][r];
}

// ---------------- flash attention ----------------------------------------------
// grid (S/128, H, B) with XCD-chunked swizzle; block 256 = 4 waves; wave owns
// 32 q-rows. KT=64, K/V double-buffered LDS, ONE lgkmcnt-only barrier per tile
// (ds_write(nb) ordering only; global reg-prefetch stays in flight across it).
// Swapped QK^T: lane holds P[q=row16][k=st*16+oct*4+r]; PV A-frag packed
// lane-locally via v_cvt_pk_bf16_f32; row-sum l via ones-MFMA in o_acc layout.
__global__ __launch_bounds__(256, 2)
void flash_attn(const u16* __restrict__ qkb, const u16* __restrict__ vTp,
                const float* __restrict__ biasT, u16* __restrict__ ctx) {
  const int S = 2048, LDQ = 2048;
  // XCD-chunked bijection: 512 blocks, 8 XCDs, 64 blocks/XCD.
  const int lin = blockIdx.x + (blockIdx.y << 4) + (blockIdx.z << 8);
  const int V = (lin & 7) * 64 + (lin >> 3);
  const int qt0 = (V & 15) * 128;
  const int h = (V >> 4) & 15, b = V >> 8;
  const int tid = threadIdx.x, wid = tid >> 6, lane = tid & 63;
  const int row16 = lane & 15, oct = lane >> 4;

  __shared__ __align__(16) float biasS[2176];
  __shared__ __align__(16) u16 Ks[2][2][64][40];   // [buf][d-half][k-row][pitch]
  __shared__ __align__(16) u16 Vts[2][2][64][40];  // [buf][ks][d][pitch]

  {
    const float* bsrc = biasT + h * 4096 + (1920 - qt0);
    for (int i = tid; i < 544; i += 256)
      ((float4v*)biasS)[i] = ((const float4v*)bsrc)[i];
  }
  const float bias_neg = biasT[h * 4096];          // d <= -128 (bucket 15)
  const float bias_pos = biasT[h * 4096 + 4094];   // d >= +128 (bucket 31)

  const u16* qbase = qkb + ((size_t)b * S + qt0 + wid * 32) * LDQ + h * 64;
  short8 qf[2][2];
#pragma unroll
  for (int f = 0; f < 2; f++)
#pragma unroll
    for (int hd = 0; hd < 2; hd++)
      qf[f][hd] = *(const short8*)(qbase + (size_t)(f * 16 + row16) * LDQ + hd * 32 + oct * 8);

  float4v l_acc[2] = {};
  float4v o_acc[2][4] = {};
  const short8 ones = {0x3F80, 0x3F80, 0x3F80, 0x3F80, 0x3F80, 0x3F80, 0x3F80, 0x3F80};

  const int sr = lane >> 2, c8 = (lane & 3) * 8;
  const int srow = wid * 16 + sr;
  const u16* Kst = qkb + 1024 + ((size_t)b * S + srow) * LDQ + c8 + h * 64;
  const u16* Vst = vTp + ((size_t)(b * 16 + h) * 64 + srow) * 2048 + c8;

  short8 kreg[2], vreg[2];
  // prologue: stage tile 0 into buf0, load tile 1 into regs, barrier
#pragma unroll
  for (int hd = 0; hd < 2; hd++) kreg[hd] = *(const short8*)(Kst + hd * 32);
#pragma unroll
  for (int ks = 0; ks < 2; ks++) vreg[ks] = *(const short8*)(Vst + ks * 32);
#pragma unroll
  for (int hd = 0; hd < 2; hd++) *(short8*)&Ks[0][hd][srow][c8] = kreg[hd];
#pragma unroll
  for (int ks = 0; ks < 2; ks++) *(short8*)&Vts[0][ks][srow][c8] = vreg[ks];
#pragma unroll
  for (int hd = 0; hd < 2; hd++) kreg[hd] = *(const short8*)(Kst + (size_t)64 * LDQ + hd * 32);
#pragma unroll
  for (int ks = 0; ks < 2; ks++) vreg[ks] = *(const short8*)(Vst + 64 + ks * 32);
  __syncthreads();

  for (int kt = 0; kt < S; kt += 64) {
    const int cur = (kt >> 6) & 1, nb = cur ^ 1;
    // write next tile into other buffer (no barrier needed: nb's last readers
    // finished before the barrier that ended the previous iteration)
    if (kt + 64 < S) {
#pragma unroll
      for (int hd = 0; hd < 2; hd++) *(short8*)&Ks[nb][hd][srow][c8] = kreg[hd];
#pragma unroll
      for (int ks = 0; ks < 2; ks++) *(short8*)&Vts[nb][ks][srow][c8] = vreg[ks];
    }
    // prefetch tile kt+128 into regs (hidden under compute; NOT drained at the
    // tile barrier -- compiler inserts counted vmcnt before next-tile ds_write)
    if (kt + 128 < S) {
#pragma unroll
      for (int hd = 0; hd < 2; hd++)
        kreg[hd] = *(const short8*)(Kst + (size_t)(kt + 128) * LDQ + hd * 32);
#pragma unroll
      for (int ks = 0; ks < 2; ks++)
        vreg[ks] = *(const short8*)(Vst + (kt + 128) + ks * 32);
    }

    short8 kf[4][2];
#pragma unroll
    for (int st = 0; st < 4; st++)
#pragma unroll
      for (int hd = 0; hd < 2; hd++)
        kf[st][hd] = *(const short8*)&Ks[cur][hd][st * 16 + row16][oct * 8];

    // swapped QK^T: lane holds S[k = st*16 + oct*4 + r][q = row16]
    float4v sc[2][4];
    __builtin_amdgcn_s_setprio(1);
#pragma unroll
    for (int f = 0; f < 2; f++)
#pragma unroll
      for (int st = 0; st < 4; st++) {
        float4v s = {};
        s = __builtin_amdgcn_mfma_f32_16x16x32_bf16(kf[st][0], qf[f][0], s, 0, 0, 0);
        s = __builtin_amdgcn_mfma_f32_16x16x32_bf16(kf[st][1], qf[f][1], s, 0, 0, 0);
        sc[f][st] = s;
      }
    __builtin_amdgcn_s_setprio(0);

    short8 vf[2][4];
#pragma unroll
    for (int ks = 0; ks < 2; ks++)
#pragma unroll
      for (int ni = 0; ni < 4; ni++)
        vf[ks][ni] = *(const short8*)&Vts[cur][ks][ni * 16 + row16][oct * 8];

    // bias + exp (swapped layout: q = row16, k = st*16 + oct*4 + r)
    const int dk = kt - qt0;
    const bool far = (dk >= 256) || (dk <= -192);
    if (far) {
      const float bc = (dk > 0) ? bias_pos : bias_neg;
#pragma unroll
      for (int f = 0; f < 2; f++)
#pragma unroll
        for (int st = 0; st < 4; st++)
#pragma unroll
          for (int r = 0; r < 4; r++)
            sc[f][st][r] = __builtin_amdgcn_exp2f(__builtin_fmaf(sc[f][st][r], L2E, bc));
    } else {
#pragma unroll
      for (int f = 0; f < 2; f++) {
        const int basef = kt + oct * 4 - wid * 32 - f * 16 - row16 + 127;
#pragma unroll
        for (int st = 0; st < 4; st++)
#pragma unroll
          for (int r = 0; r < 4; r++)
            sc[f][st][r] = __builtin_amdgcn_exp2f(
                __builtin_fmaf(sc[f][st][r], L2E, biasS[basef + st * 16 + r]));
      }
    }

#pragma unroll
    for (int f = 0; f < 2; f++) {
      // lane-local P pack -> PV A-fragment (kk slot j: st = 2ks + (j>=4), r = j&3)
#pragma unroll
      for (int ks = 0; ks < 2; ks++) {
        uint4v pw;
        pw.x = cvt_pk_bf16(sc[f][2 * ks][0], sc[f][2 * ks][1]);
        pw.y = cvt_pk_bf16(sc[f][2 * ks][2], sc[f][2 * ks][3]);
        pw.z = cvt_pk_bf16(sc[f][2 * ks + 1][0], sc[f][2 * ks + 1][1]);
        pw.w = cvt_pk_bf16(sc[f][2 * ks + 1][2], sc[f][2 * ks + 1][3]);
        short8 pf = __builtin_bit_cast(short8, pw);
        __builtin_amdgcn_s_setprio(1);
#pragma unroll
        for (int ni = 0; ni < 4; ni++)
          o_acc[f][ni] = __builtin_amdgcn_mfma_f32_16x16x32_bf16(pf, vf[ks][ni], o_acc[f][ni], 0, 0, 0);
        // row-sum: D[q][*] += sum_k P[q][k]  (B = 1.0) -- same layout as o_acc
        l_acc[f] = __builtin_amdgcn_mfma_f32_16x16x32_bf16(pf, ones, l_acc[f], 0, 0, 0);
        __builtin_amdgcn_s_setprio(0);
      }
    }
    // LDS-only barrier: order this tile's ds ops (reads of cur, writes of nb)
    // against next iteration, WITHOUT draining the private global prefetch.
    asm volatile("s_waitcnt lgkmcnt(0)" ::: "memory");
    __builtin_amdgcn_s_barrier();
    __builtin_amdgcn_sched_barrier(0);
  }

  // epilogue: l_acc[f][r] is the row-sum for q = ... + oct*4 + r (o_acc rows)
#pragma unroll
  for (int f = 0; f < 2; f++) {
    float linv[4];
#pragma unroll
    for (int r = 0; r < 4; r++)
      linv[r] = 1.0f / l_acc[f][r];
    const size_t orow = (size_t)b * S + qt0 + wid * 32 + f * 16 + oct * 4;
#pragma unroll
    for (int ni = 0; ni < 4; ni++)
#pragma unroll
      for (int r = 0; r < 4; r++)
        ctx[(orow + r) * 1024 + h * 64 + ni * 16 + row16] = f2b_fast(o_acc[f][ni][r] * linv[r]);
  }
}

// ---------------- host launcher ------------------------------------------------
extern "C" void kernel_launch(void* const* d_in, const int* in_sizes, int n_in,
                              void* d_out, int out_size, void* d_ws, size_t ws_size,
                              hipStream_t stream) {
  const float* x        = (const float*)d_in[0];
  const float* q_w      = (const float*)d_in[1];
  const float* k_w      = (const float*)d_in[2];
  const float* v_w      = (const float*)d_in[3];
  const float* o_w      = (const float*)d_in[4];
  const float* rel_bias = (const float*)d_in[5];

  char* ws = (char*)d_ws;
  u16*   xb    = (u16*)(ws);                         // [0,8M)   x bf16
  u16*   wqkv  = (u16*)(ws + 8388608);               // [8M,14M) qkv weights bf16
  u16*   owb   = (u16*)(ws + 14680064);              // [14M,16M) o_w bf16
  u16*   qkb   = (u16*)(ws + 16777216);              // [16M,32M) Q|K rows, LDC=2048
  u16*   vTp   = (u16*)(ws + 33554432);              // [32M,40M) V^T permuted
  u16*   ctxb  = (u16*)(ws + 41943040);              // [40M,48M) attention out bf16
  float* biasT = (float*)(ws + 50331648);            // [48M..] bias table

  cvt_all<<<8448, 256, 0, stream>>>(x, q_w, k_w, v_w, o_w, rel_bias,
                                    xb, wqkv, owb, biasT);

  dim3 g1(4096 / 128, 3072 / 128);
  gemm_qkv<<<g1, 256, 0, stream>>>(xb, wqkv, qkb, vTp);

  dim3 g2(2048 / 128, 16, 2);
  flash_attn<<<g2, 256, 0, stream>>>(qkb, vTp, biasT, ctxb);

  dim3 g3(4096 / 64, 1024 / 128);
  gemm_out<<<g3, 256, 0, stream>>>(ctxb, owb, (float*)d_out);
}